// Round 1
// baseline (2128.000 us; speedup 1.0000x reference)
//
#include <hip/hip_runtime.h>
#include <hip/hip_bf16.h>

#define N_EDGES 1000000
#define N_NODES 500000
#define N_TRIS  600000

typedef __attribute__((ext_vector_type(8))) short bf16x8;
typedef __attribute__((ext_vector_type(4))) float f32x4;
typedef __attribute__((ext_vector_type(2))) float f32x2;

// tanh via exp2-based __expf; clamp keeps e^{2z} finite, tanh(15) == 1.0f in f32.
__device__ __forceinline__ float fast_tanh(float z) {
    z = fminf(fmaxf(z, -15.0f), 15.0f);
    float e = __expf(2.0f * z);
    return (e - 1.0f) / (e + 1.0f);
}

// Packed 2xf32 atomic add when HW/builtin available (CDNA3+ has *_atomic_pk_add_f32);
// falls back to two f32 atomics (== previous kernel's behavior).
__device__ __forceinline__ void atomic_pk_add(float* p, f32x2 v) {
#if __has_builtin(__builtin_amdgcn_flat_atomic_fadd_v2f32)
    __builtin_amdgcn_flat_atomic_fadd_v2f32((f32x2*)p, v);
#else
    unsafeAtomicAdd(p, v.x);
    unsafeAtomicAdd(p + 1, v.y);
#endif
}

__device__ __forceinline__ short bf16_hi_bits(float v, float& hv) {
    __hip_bfloat16 h = __float2bfloat16(v);
    hv = __bfloat162float(h);
    short s; __builtin_memcpy(&s, &h, 2); return s;
}
__device__ __forceinline__ short bf16_bits(float v) {
    __hip_bfloat16 h = __float2bfloat16(v);
    short s; __builtin_memcpy(&s, &h, 2); return s;
}

// One thread per (edge, channel-pair). x read fully coalesced; 2 packed atomics into y.
__global__ __launch_bounds__(256) void k_scatter_y(
    const float* __restrict__ x, const int* __restrict__ en, float* __restrict__ y)
{
    int idx = blockIdx.x * 256 + threadIdx.x;
    int e = idx >> 5, c2 = idx & 31;
    f32x2 v = ((const f32x2*)x)[(size_t)e * 32 + c2];
    int tail = en[2 * e];
    int head = en[2 * e + 1];
    atomic_pk_add(&y[(size_t)tail * 64 + 2 * c2], -v);
    atomic_pk_add(&y[(size_t)head * 64 + 2 * c2],  v);
}

// One thread per (triangle, channel-pair). 3 row gathers + 3 packed atomics.
__global__ __launch_bounds__(256) void k_scatter_z1e(
    const float* __restrict__ x, const int* __restrict__ te, float* __restrict__ z1e)
{
    int idx = blockIdx.x * 256 + threadIdx.x;
    int t = idx >> 5, c2 = idx & 31;
    int e0 = te[3 * t], e1 = te[3 * t + 1], e2 = te[3 * t + 2];
    const f32x2* x2 = (const f32x2*)x;
    f32x2 w = x2[(size_t)e0 * 32 + c2] - x2[(size_t)e1 * 32 + c2] + x2[(size_t)e2 * 32 + c2];
    atomic_pk_add(&z1e[(size_t)e0 * 64 + 2 * c2],  w);
    atomic_pk_add(&z1e[(size_t)e1 * 64 + 2 * c2], -w);
    atomic_pk_add(&z1e[(size_t)e2 * 64 + 2 * c2],  w);
}

// Fused split-bf16 MFMA GEMM + tanh epilogue:
//   out = tanh([z1e | x | y_head - y_tail] @ [w2; w1; w0])   (K = 192, N = 64)
// v2 structure:
//  - wave w owns COLUMN strip [w*16, w*16+16) x all 64 rows; its 6x2 B-fragments
//    (hi/lo split of the W column strip) are loaded ONCE from global into 48 VGPRs.
//    No W LDS, no per-block W staging loop.
//  - A chunk (64 rows x 32 k) double-buffered in LDS, AST=40 (80 B stride:
//    (5r+q) mod 8 is a permutation -> <=2-way bank alias = free).
//  - 1 barrier per chunk: stage(c) -> issue loads(c+1) -> barrier -> MFMA(c);
//    gather latency hides under MFMA of the previous chunk.
//  - A staged with 2x ds_write_b128 per thread (was 16x ds_write_b16).
#define AST 40

__global__ __launch_bounds__(256, 3) void k_final(
    const float* __restrict__ x, const int* __restrict__ en,
    const float* __restrict__ y, float* __restrict__ zio,
    const float* __restrict__ w0, const float* __restrict__ w1,
    const float* __restrict__ w2)
{
    __shared__ short Ahi[2][64 * AST];
    __shared__ short Alo[2][64 * AST];
    __shared__ int nidx[128];                  // [0..63]=tail, [64..127]=head

    const int t     = threadIdx.x;
    const int ebase = blockIdx.x * 64;
    const int lane  = t & 63;
    const int w     = t >> 6;                  // wave id -> column strip
    const int mrow  = lane & 15;
    const int quad  = lane >> 4;

    // B fragments in registers: lane holds W[k = ch*32 + quad*8 + j][n = w*16 + mrow].
    bf16x8 Bhi[6], Blo[6];
    {
        const int n = w * 16 + mrow;
        #pragma unroll
        for (int ch = 0; ch < 6; ++ch) {
            const float* Wsrc = (ch < 2) ? w2 : ((ch < 4) ? w1 : w0);
            const int kb = (ch & 1) * 32 + quad * 8;
            bf16x8 bh, bl;
            #pragma unroll
            for (int j = 0; j < 8; ++j) {
                float v = Wsrc[(kb + j) * 64 + n];
                float hv;
                bh[j] = bf16_hi_bits(v, hv);
                bl[j] = bf16_bits(v - hv);
            }
            Bhi[ch] = bh; Blo[ch] = bl;
        }
    }

    if (t < 128) nidx[t] = en[2 * (ebase + (t & 63)) + (t >> 6)];

    const int r    = t >> 2;                   // staging: row 0..63
    const int q    = t & 3;                    // staging: 8-float group
    const int koff = q * 8;

    f32x4 acc[4] = {{0,0,0,0},{0,0,0,0},{0,0,0,0},{0,0,0,0}};

    float4 pa0, pa1, pb0, pb1;                 // prefetch regs (pb* only for y chunks)

    // prologue: issue chunk-0 loads (zio, low half)
    {
        const float4* s = (const float4*)(zio + (size_t)(ebase + r) * 64 + koff);
        pa0 = s[0]; pa1 = s[1];
    }

    #pragma unroll
    for (int ch = 0; ch < 6; ++ch) {
        const int b = ch & 1;

        // stage current chunk into LDS buffer b (split hi/lo, packed 16B writes)
        {
            float vv[8];
            if (ch >= 4) {
                vv[0] = pa0.x - pb0.x; vv[1] = pa0.y - pb0.y;
                vv[2] = pa0.z - pb0.z; vv[3] = pa0.w - pb0.w;
                vv[4] = pa1.x - pb1.x; vv[5] = pa1.y - pb1.y;
                vv[6] = pa1.z - pb1.z; vv[7] = pa1.w - pb1.w;
            } else {
                vv[0] = pa0.x; vv[1] = pa0.y; vv[2] = pa0.z; vv[3] = pa0.w;
                vv[4] = pa1.x; vv[5] = pa1.y; vv[6] = pa1.z; vv[7] = pa1.w;
            }
            bf16x8 hi, lo;
            #pragma unroll
            for (int j = 0; j < 8; ++j) {
                float hv;
                hi[j] = bf16_hi_bits(vv[j], hv);
                lo[j] = bf16_bits(vv[j] - hv);
            }
            *(bf16x8*)&Ahi[b][r * AST + koff] = hi;
            *(bf16x8*)&Alo[b][r * AST + koff] = lo;
        }

        // issue next chunk's global loads; they complete under this chunk's MFMAs
        if (ch < 5) {
            const int nc  = ch + 1;
            const int off = (nc & 1) * 32 + koff;
            if (nc < 2) {
                const float4* s = (const float4*)(zio + (size_t)(ebase + r) * 64 + off);
                pa0 = s[0]; pa1 = s[1];
            } else if (nc < 4) {
                const float4* s = (const float4*)(x + (size_t)(ebase + r) * 64 + off);
                pa0 = s[0]; pa1 = s[1];
            } else {
                const float4* sh = (const float4*)(y + (size_t)nidx[64 + r] * 64 + off);
                const float4* st = (const float4*)(y + (size_t)nidx[r]      * 64 + off);
                pa0 = sh[0]; pa1 = sh[1]; pb0 = st[0]; pb1 = st[1];
            }
        }

        __syncthreads();

        #pragma unroll
        for (int mt = 0; mt < 4; ++mt) {
            const bf16x8 ah = *(const bf16x8*)&Ahi[b][(mt * 16 + mrow) * AST + quad * 8];
            const bf16x8 al = *(const bf16x8*)&Alo[b][(mt * 16 + mrow) * AST + quad * 8];
            acc[mt] = __builtin_amdgcn_mfma_f32_16x16x32_bf16(ah, Bhi[ch], acc[mt], 0, 0, 0);
            acc[mt] = __builtin_amdgcn_mfma_f32_16x16x32_bf16(al, Bhi[ch], acc[mt], 0, 0, 0);
            acc[mt] = __builtin_amdgcn_mfma_f32_16x16x32_bf16(ah, Blo[ch], acc[mt], 0, 0, 0);
        }
    }

    // D layout: row = quad*4 + i (within mt strip), col = mrow (within wave's strip).
    #pragma unroll
    for (int mt = 0; mt < 4; ++mt) {
        #pragma unroll
        for (int i = 0; i < 4; ++i) {
            int e = ebase + mt * 16 + quad * 4 + i;
            int c = w * 16 + mrow;
            zio[(size_t)e * 64 + c] = fast_tanh(acc[mt][i]);
        }
    }
}

extern "C" void kernel_launch(void* const* d_in, const int* in_sizes, int n_in,
                              void* d_out, int out_size, void* d_ws, size_t ws_size,
                              hipStream_t stream) {
    const float* x  = (const float*)d_in[0];
    const int*   en = (const int*)d_in[1];
    const int*   te = (const int*)d_in[2];
    const float* w0 = (const float*)d_in[3];
    const float* w1 = (const float*)d_in[4];
    const float* w2 = (const float*)d_in[5];
    float* out = (float*)d_out;          // doubles as z1e scratch
    float* y   = (float*)d_ws;           // 128 MB

    hipMemsetAsync(y,   0, (size_t)N_NODES * 64 * sizeof(float), stream);
    hipMemsetAsync(out, 0, (size_t)N_EDGES * 64 * sizeof(float), stream);

    k_scatter_y  <<<(N_EDGES * 32) / 256, 256, 0, stream>>>(x, en, y);
    k_scatter_z1e<<<(N_TRIS  * 32) / 256, 256, 0, stream>>>(x, te, out);
    k_final      <<<N_EDGES / 64,         256, 0, stream>>>(x, en, y, out, w0, w1, w2);
}

// Round 4
// 1762.578 us; speedup vs baseline: 1.2073x; 1.2073x over previous
//
#include <hip/hip_runtime.h>
#include <hip/hip_bf16.h>

#define N_EDGES 1000000
#define N_NODES 500000
#define N_TRIS  600000
#define MAXDEG  64          // defensive clamp; true max degree << 64

typedef __attribute__((ext_vector_type(8))) short bf16x8;
typedef __attribute__((ext_vector_type(4))) float f32x4;

// tanh via exp2-based __expf; clamp keeps e^{2z} finite, tanh(15) == 1.0f in f32.
__device__ __forceinline__ float fast_tanh(float z) {
    z = fminf(fmaxf(z, -15.0f), 15.0f);
    float e = __expf(2.0f * z);
    return (e - 1.0f) / (e + 1.0f);
}

__device__ __forceinline__ short bf16_hi_bits(float v, float& hv) {
    __hip_bfloat16 h = __float2bfloat16(v);
    hv = __bfloat162float(h);
    short s; __builtin_memcpy(&s, &h, 2); return s;
}
__device__ __forceinline__ short bf16_bits(float v) {
    __hip_bfloat16 h = __float2bfloat16(v);
    short s; __builtin_memcpy(&s, &h, 2); return s;
}

// ---------------- CSR build: histogram -> 2-level exclusive scan -> fill ----
#define SCAN_BLOCKS 256

__global__ __launch_bounds__(256) void k_hist_n(const int* __restrict__ en, int* __restrict__ cnt) {
    int e = blockIdx.x * 256 + threadIdx.x;
    if (e >= N_EDGES) return;
    atomicAdd(&cnt[en[2 * e]], 1);
    atomicAdd(&cnt[en[2 * e + 1]], 1);
}

__global__ __launch_bounds__(256) void k_hist_e(const int* __restrict__ te, int* __restrict__ cnt) {
    int t = blockIdx.x * 256 + threadIdx.x;
    if (t >= N_TRIS) return;
    atomicAdd(&cnt[te[3 * t]], 1);
    atomicAdd(&cnt[te[3 * t + 1]], 1);
    atomicAdd(&cnt[te[3 * t + 2]], 1);
}

__global__ __launch_bounds__(256) void k_scan_reduce(
    const int* __restrict__ cnt, int N, int chunk, int* __restrict__ bsum)
{
    __shared__ int red[256];
    int b = blockIdx.x, t = threadIdx.x;
    int lo = b * chunk, hi = lo + chunk; if (hi > N) hi = N;
    int s = 0;
    for (int i = lo + t; i < hi; i += 256) s += cnt[i];
    red[t] = s; __syncthreads();
    for (int o = 128; o; o >>= 1) { if (t < o) red[t] += red[t + o]; __syncthreads(); }
    if (t == 0) bsum[b] = red[0];
}

__global__ __launch_bounds__(256) void k_scan_base(int* __restrict__ bsum) {
    __shared__ int sh[256];
    int t = threadIdx.x;
    int v0 = bsum[t];
    sh[t] = v0; __syncthreads();
    for (int o = 1; o < 256; o <<= 1) {
        int u = (t >= o) ? sh[t - o] : 0;
        __syncthreads();
        sh[t] += u;
        __syncthreads();
    }
    bsum[t] = sh[t] - v0;   // exclusive
}

__global__ __launch_bounds__(256) void k_scan_write(
    const int* __restrict__ cnt, int N, int chunk,
    const int* __restrict__ bsum, int* __restrict__ off, int total)
{
    __shared__ int sh[256];
    int b = blockIdx.x, t = threadIdx.x;
    int lo = b * chunk, hi = lo + chunk; if (hi > N) hi = N;
    int base = bsum[b];
    for (int s0 = lo; s0 < hi; s0 += 256) {
        int i = s0 + t;
        int v = (i < hi) ? cnt[i] : 0;
        sh[t] = v; __syncthreads();
        for (int o = 1; o < 256; o <<= 1) {
            int u = (t >= o) ? sh[t - o] : 0;
            __syncthreads();
            sh[t] += u;
            __syncthreads();
        }
        if (i < hi) off[i] = base + sh[t] - v;
        base += sh[255];
        __syncthreads();
    }
    if (b == SCAN_BLOCKS - 1 && t == 0) off[N] = total;
}

// node CSR entries: edge id, bit31 set => tail slot (sign -1), else head (+1)
__global__ __launch_bounds__(256) void k_fill_n(
    const int* __restrict__ en, const int* __restrict__ off,
    int* __restrict__ cur, int* __restrict__ ent)
{
    int e = blockIdx.x * 256 + threadIdx.x;
    if (e >= N_EDGES) return;
    int tail = en[2 * e], head = en[2 * e + 1];
    int pt = off[tail] + atomicAdd(&cur[tail], 1);
    ent[pt] = e | 0x80000000;
    int ph = off[head] + atomicAdd(&cur[head], 1);
    ent[ph] = e;
}

// edge CSR entries: tri*4 + slot (slot 0,2 -> +w ; slot 1 -> -w)
__global__ __launch_bounds__(256) void k_fill_e(
    const int* __restrict__ te, const int* __restrict__ off,
    int* __restrict__ cur, int* __restrict__ ent)
{
    int t = blockIdx.x * 256 + threadIdx.x;
    if (t >= N_TRIS) return;
    #pragma unroll
    for (int s = 0; s < 3; ++s) {
        int e = te[3 * t + s];
        int p = off[e] + atomicAdd(&cur[e], 1);
        ent[p] = t * 4 + s;
    }
}

// ---------------- z1e gather: one wave per edge, lane = channel ------------
// z1e[e] = sum over incident tris t: sign(slot) * (x[e0]-x[e1]+x[e2])
__global__ __launch_bounds__(256) void k_z1e(
    const float* __restrict__ x, const int* __restrict__ te,
    const int* __restrict__ off, const int* __restrict__ ent,
    float* __restrict__ out)
{
    int gid = blockIdx.x * 256 + threadIdx.x;
    int e = gid >> 6, c = gid & 63;
    int i0 = off[e];
    int len = off[e + 1] - i0;
    len = (len < 0) ? 0 : ((len > MAXDEG) ? MAXDEG : len);   // defensive
    float acc = 0.f;
    for (int i = i0; i < i0 + len; ++i) {
        int u = ent[i];
        int t = u >> 2, s = u & 3;
        int e0 = te[3 * t], e1 = te[3 * t + 1], e2 = te[3 * t + 2];
        float w = x[(size_t)e0 * 64 + c] - x[(size_t)e1 * 64 + c] + x[(size_t)e2 * 64 + c];
        acc += (s == 1) ? -w : w;
    }
    out[(size_t)e * 64 + c] = acc;
}

// ---------------- fused GEMM + tanh, with on-the-fly y-diff gather ---------
//   out = tanh([z1e | x | y_head - y_tail] @ [w2; w1; w0])   (K = 192, N = 64)
//  - wave w owns column strip [w*16,w*16+16); its 6x2 split-bf16 B-fragments
//    live in 48 VGPRs (loaded once from global, L2-hot). No W LDS.
//  - y never materialized: per row r, y[head]-y[tail] = signed sum of x rows
//    over the two node adjacency lists (node CSR), gathered into 16 regs.
//  - A chunk (64x32) double-buffered in LDS, AST=40 (80 B stride -> <=2-way
//    bank alias = free). 1 barrier per chunk.
#define AST 40

__global__ __launch_bounds__(256, 3) void k_final(
    const float* __restrict__ x, const int* __restrict__ en,
    const int* __restrict__ offn, const int* __restrict__ entn,
    float* __restrict__ zio,
    const float* __restrict__ w0, const float* __restrict__ w1,
    const float* __restrict__ w2)
{
    __shared__ short Ahi[2][64 * AST];
    __shared__ short Alo[2][64 * AST];
    __shared__ int sA[128], sB[128];   // [0..63]=tail list, [64..127]=head list

    const int t     = threadIdx.x;
    const int ebase = blockIdx.x * 64;
    const int lane  = t & 63;
    const int w     = t >> 6;
    const int mrow  = lane & 15;
    const int quad  = lane >> 4;

    // B fragments: lane holds W[k = ch*32 + quad*8 + j][n = w*16 + mrow].
    bf16x8 Bhi[6], Blo[6];
    {
        const int n = w * 16 + mrow;
        #pragma unroll
        for (int ch = 0; ch < 6; ++ch) {
            const float* Wsrc = (ch < 2) ? w2 : ((ch < 4) ? w1 : w0);
            const int kb = (ch & 1) * 32 + quad * 8;
            bf16x8 bh, bl;
            #pragma unroll
            for (int j = 0; j < 8; ++j) {
                float v = Wsrc[(kb + j) * 64 + n];
                float hv;
                bh[j] = bf16_hi_bits(v, hv);
                bl[j] = bf16_bits(v - hv);
            }
            Bhi[ch] = bh; Blo[ch] = bl;
        }
    }

    if (t < 128) {
        int n = en[2 * (ebase + (t & 63)) + (t >> 6)];
        sA[t] = offn[n];
        sB[t] = offn[n + 1];
    }

    const int r    = t >> 2;       // staging: row 0..63
    const int q    = t & 3;        // staging: 8-float group
    const int koff = q * 8;

    __syncthreads();               // sA/sB visible

    // Gather y[head_r] - y[tail_r], channels [koff..koff+8) and [32+koff..):
    float yd[16];
    #pragma unroll
    for (int j = 0; j < 16; ++j) yd[j] = 0.f;
    for (int pass = 0; pass < 2; ++pass) {
        const float ps = pass ? -1.f : 1.f;         // head +, tail -
        const int li = pass ? r : 64 + r;
        int i0 = sA[li];
        int len = sB[li] - i0;
        len = (len < 0) ? 0 : ((len > MAXDEG) ? MAXDEG : len);   // defensive
        for (int i = i0; i < i0 + len; ++i) {
            int u = entn[i];
            float s = (u < 0) ? -ps : ps;
            const float* xr = x + (size_t)(u & 0x7fffffff) * 64 + koff;
            float4 a0 = *(const float4*)(xr);
            float4 a1 = *(const float4*)(xr + 4);
            float4 b0 = *(const float4*)(xr + 32);
            float4 b1 = *(const float4*)(xr + 36);
            yd[0]  += s * a0.x; yd[1]  += s * a0.y; yd[2]  += s * a0.z; yd[3]  += s * a0.w;
            yd[4]  += s * a1.x; yd[5]  += s * a1.y; yd[6]  += s * a1.z; yd[7]  += s * a1.w;
            yd[8]  += s * b0.x; yd[9]  += s * b0.y; yd[10] += s * b0.z; yd[11] += s * b0.w;
            yd[12] += s * b1.x; yd[13] += s * b1.y; yd[14] += s * b1.z; yd[15] += s * b1.w;
        }
    }

    f32x4 acc[4] = {{0,0,0,0},{0,0,0,0},{0,0,0,0},{0,0,0,0}};
    float4 pa0, pa1;

    // prologue: chunk-0 loads (zio = z1e, low half)
    {
        const float4* s = (const float4*)(zio + (size_t)(ebase + r) * 64 + koff);
        pa0 = s[0]; pa1 = s[1];
    }

    #pragma unroll
    for (int ch = 0; ch < 6; ++ch) {
        const int b = ch & 1;

        // stage current chunk into LDS buffer b (split hi/lo, 16B writes)
        {
            float vv[8];
            if (ch >= 4) {
                #pragma unroll
                for (int j = 0; j < 8; ++j) vv[j] = yd[(ch - 4) * 8 + j];
            } else {
                vv[0] = pa0.x; vv[1] = pa0.y; vv[2] = pa0.z; vv[3] = pa0.w;
                vv[4] = pa1.x; vv[5] = pa1.y; vv[6] = pa1.z; vv[7] = pa1.w;
            }
            bf16x8 hi, lo;
            #pragma unroll
            for (int j = 0; j < 8; ++j) {
                float hv;
                hi[j] = bf16_hi_bits(vv[j], hv);
                lo[j] = bf16_bits(vv[j] - hv);
            }
            *(bf16x8*)&Ahi[b][r * AST + koff] = hi;
            *(bf16x8*)&Alo[b][r * AST + koff] = lo;
        }

        // issue next chunk's global loads (chunks 1..3 only; 4,5 are in regs)
        if (ch < 3) {
            const int nc  = ch + 1;
            const int off = (nc & 1) * 32 + koff;
            const float* src = (nc < 2) ? zio : x;
            const float4* s = (const float4*)(src + (size_t)(ebase + r) * 64 + off);
            pa0 = s[0]; pa1 = s[1];
        }

        __syncthreads();

        #pragma unroll
        for (int mt = 0; mt < 4; ++mt) {
            const bf16x8 ah = *(const bf16x8*)&Ahi[b][(mt * 16 + mrow) * AST + quad * 8];
            const bf16x8 al = *(const bf16x8*)&Alo[b][(mt * 16 + mrow) * AST + quad * 8];
            acc[mt] = __builtin_amdgcn_mfma_f32_16x16x32_bf16(ah, Bhi[ch], acc[mt], 0, 0, 0);
            acc[mt] = __builtin_amdgcn_mfma_f32_16x16x32_bf16(al, Bhi[ch], acc[mt], 0, 0, 0);
            acc[mt] = __builtin_amdgcn_mfma_f32_16x16x32_bf16(ah, Blo[ch], acc[mt], 0, 0, 0);
        }
    }

    // D layout: row = quad*4 + i (within mt strip), col = mrow (wave strip).
    #pragma unroll
    for (int mt = 0; mt < 4; ++mt) {
        #pragma unroll
        for (int i = 0; i < 4; ++i) {
            int e = ebase + mt * 16 + quad * 4 + i;
            int c = w * 16 + mrow;
            zio[(size_t)e * 64 + c] = fast_tanh(acc[mt][i]);
        }
    }
}

extern "C" void kernel_launch(void* const* d_in, const int* in_sizes, int n_in,
                              void* d_out, int out_size, void* d_ws, size_t ws_size,
                              hipStream_t stream) {
    const float* x  = (const float*)d_in[0];
    const int*   en = (const int*)d_in[1];
    const int*   te = (const int*)d_in[2];
    const float* w0 = (const float*)d_in[3];
    const float* w1 = (const float*)d_in[4];
    const float* w2 = (const float*)d_in[5];
    float* out = (float*)d_out;          // z1e scratch, then final output

    // workspace layout (ints), ~27.2 MB total
    int* off_n = (int*)d_ws;             // 500001
    int* cnt_n = off_n + 500001;         // 500000
    int* ent_n = cnt_n + 500000;         // 2000000
    int* off_e = ent_n + 2000000;        // 1000001
    int* cnt_e = off_e + 1000001;        // 1000000
    int* ent_e = cnt_e + 1000000;        // 1800000
    int* bsum  = ent_e + 1800000;        // 256

    const int CH_N = (N_NODES + SCAN_BLOCKS - 1) / SCAN_BLOCKS;  // 1954
    const int CH_E = (N_EDGES + SCAN_BLOCKS - 1) / SCAN_BLOCKS;  // 3907

    hipMemsetAsync(cnt_n, 0, (size_t)N_NODES * 4, stream);
    hipMemsetAsync(cnt_e, 0, (size_t)N_EDGES * 4, stream);

    // node CSR
    k_hist_n<<<(N_EDGES + 255) / 256, 256, 0, stream>>>(en, cnt_n);
    k_scan_reduce<<<SCAN_BLOCKS, 256, 0, stream>>>(cnt_n, N_NODES, CH_N, bsum);
    k_scan_base<<<1, 256, 0, stream>>>(bsum);
    k_scan_write<<<SCAN_BLOCKS, 256, 0, stream>>>(cnt_n, N_NODES, CH_N, bsum, off_n, 2 * N_EDGES);
    hipMemsetAsync(cnt_n, 0, (size_t)N_NODES * 4, stream);
    k_fill_n<<<(N_EDGES + 255) / 256, 256, 0, stream>>>(en, off_n, cnt_n, ent_n);

    // edge CSR (from triangles)
    k_hist_e<<<(N_TRIS + 255) / 256, 256, 0, stream>>>(te, cnt_e);
    k_scan_reduce<<<SCAN_BLOCKS, 256, 0, stream>>>(cnt_e, N_EDGES, CH_E, bsum);
    k_scan_base<<<1, 256, 0, stream>>>(bsum);
    k_scan_write<<<SCAN_BLOCKS, 256, 0, stream>>>(cnt_e, N_EDGES, CH_E, bsum, off_e, 3 * N_TRIS);
    hipMemsetAsync(cnt_e, 0, (size_t)N_EDGES * 4, stream);
    k_fill_e<<<(N_TRIS + 255) / 256, 256, 0, stream>>>(te, off_e, cnt_e, ent_e);

    // gather z1e into out, then fused GEMM+tanh
    k_z1e  <<<(N_EDGES * 64) / 256, 256, 0, stream>>>(x, te, off_e, ent_e, out);
    k_final<<<N_EDGES / 64,         256, 0, stream>>>(x, en, off_n, ent_n, out, w0, w1, w2);
}